// Round 8
// baseline (473.197 us; speedup 1.0000x reference)
//
#include <hip/hip_runtime.h>

#define KW 11
#define PAD 5
#define TW 32
#define TH 32
#define HROWS 16           // rows per half-tile (phase B row r needs only vv row r)
#define ICOLS 42           // input col span incl. halo (TW + KW - 1)
#define S4 45              // float4-plane row stride (ODD; 180 mod 32 = 20 -> 8 distinct b128 groups)
#define SX 45              // sx-plane row stride
#define IMH 512
#define IMW 512
#define NBLK 12288         // 16 x 16 x 48

typedef float f2 __attribute__((ext_vector_type(2)));
typedef float f4 __attribute__((ext_vector_type(4)));

// LDS layout (per 16-row half): vv4[row*S4 + col] = (mu1,mu2,q11,q22) float4
//                               vsx[row*SX + col] = x1*x2 moment (f32)
// Half-split: A0 -> bar -> B0 -> bar -> A1 -> bar -> B1. LDS 29.2 -> 14.5 KB
// lifts residency 5 -> 8 blocks/CU (wave cap at VGPR<=64).
//
// R2/R6 lesson: WRITE_SIZE above ~0.4 MB is scratch spill (R6 proved the
// "harness writeback floor" theory wrong - hoisted loads removed it all).
// R5/R6 lesson: block latency was 28 serialized HBM loads; hoisting all
// loads into distinct regs before use (MLP) cut ssim_main 199 -> 90 us.
// R3 lesson: forcing tight launch_bounds with large UNSINKABLE live state
// (accumulators) spills catastrophically; here per-phase accums <= 20 and
// loads are sinkable, so (256,8) pinning the <=64-VGPR tier is safe.

#define PHASE_A(EDGE_, H_)                                                    \
    if (t < ICOLS * 4) {                                                      \
        const int c  = t % ICOLS;                                             \
        const int rg = t / ICOLS;            /* 0..3 */                       \
        const int r0 = rg * 4;               /* local row base in half */     \
        const int gr0 = iy0 + (H_) * HROWS + r0;                              \
        const int gc = ix0 + c;                                               \
        float a1[14], a2[14];                                                 \
        if (EDGE_) {                                                          \
            const bool cok = (gc >= 0) && (gc < IMW);                         \
            _Pragma("unroll")                                                 \
            for (int i = 0; i < 14; ++i) {                                    \
                const int gr = gr0 + i;                                       \
                const bool ok = cok && (gr >= 0) && (gr < IMH);               \
                const size_t o = base + (size_t)(ok ? gr : 0) * IMW           \
                               + (ok ? gc : 0);                               \
                a1[i] = ok ? img1[o] : 0.f;                                   \
                a2[i] = ok ? img2[o] : 0.f;                                   \
            }                                                                 \
        } else {                                                              \
            /* 28 scalar loads issued back-to-back into distinct regs */      \
            _Pragma("unroll")                                                 \
            for (int i = 0; i < 14; ++i) {                                    \
                const size_t o = base + (size_t)(gr0 + i) * IMW + gc;         \
                a1[i] = img1[o];                                              \
                a2[i] = img2[o];                                              \
            }                                                                 \
        }                                                                     \
        f2 m12[4]  = {{0,0},{0,0},{0,0},{0,0}};                               \
        f2 qq[4]   = {{0,0},{0,0},{0,0},{0,0}};                               \
        float sx[4] = {0, 0, 0, 0};                                           \
        _Pragma("unroll")                                                     \
        for (int i = 0; i < 14; ++i) {                                        \
            f2 x12; x12.x = a1[i]; x12.y = a2[i];                             \
            const f2 sq = x12 * x12;                                          \
            const float sxy = a1[i] * a2[i];                                  \
            _Pragma("unroll")                                                 \
            for (int k = 0; k < 4; ++k) {                                     \
                const int j = i - k;                                          \
                if (j >= 0 && j < KW) {                                       \
                    const float w = wg[j];                                    \
                    const f2 w2 = {w, w};                                     \
                    m12[k] += w2 * x12;          /* v_pk_fma_f32 */           \
                    qq[k]  += w2 * sq;           /* v_pk_fma_f32 */           \
                    sx[k]  += w * sxy;                                        \
                }                                                             \
            }                                                                 \
        }                                                                     \
        _Pragma("unroll")                                                     \
        for (int k = 0; k < 4; ++k) {                                         \
            f4 v;                                                             \
            v.x = m12[k].x; v.y = m12[k].y;                                   \
            v.z = qq[k].x;  v.w = qq[k].y;                                    \
            vv4[(r0 + k) * S4 + c] = v;          /* ds_write_b128 */          \
            vsx[(r0 + k) * SX + c] = sx[k];      /* ds_write_b32  */          \
        }                                                                     \
    }

// Phase B: 2 output cols per thread, 16 rows x 16 col-pairs = 256 tasks.
// Output col X=2cp+k uses local cols 2cp+k+j (j=0..10) -> cc = 0..11.
#define PHASE_B(H_)                                                           \
    {                                                                         \
        const int row = t >> 4;              /* 0..15 */                      \
        const int cp  = t & 15;              /* col pair 0..15 */             \
        const f4* __restrict__ p4 = &vv4[row * S4 + cp * 2];                  \
        const float* __restrict__ px = &vsx[row * SX + cp * 2];               \
        f4 v[12]; float vx[12];                                               \
        _Pragma("unroll")                                                     \
        for (int cc = 0; cc < 12; ++cc) { v[cc] = p4[cc]; vx[cc] = px[cc]; }  \
        f2 am12[2] = {{0,0},{0,0}};                                           \
        f2 aqq[2]  = {{0,0},{0,0}};                                           \
        float asx[2] = {0, 0};                                                \
        _Pragma("unroll")                                                     \
        for (int cc = 0; cc < 12; ++cc) {                                     \
            f2 v12; v12.x = v[cc].x; v12.y = v[cc].y;                         \
            f2 vqq; vqq.x = v[cc].z; vqq.y = v[cc].w;                         \
            _Pragma("unroll")                                                 \
            for (int k = 0; k < 2; ++k) {                                     \
                const int j = cc - k;                                         \
                if (j >= 0 && j < KW) {                                       \
                    const float w = wg[j];                                    \
                    const f2 w2 = {w, w};                                     \
                    am12[k] += w2 * v12;                                      \
                    aqq[k]  += w2 * vqq;                                      \
                    asx[k]  += w * vx[cc];                                    \
                }                                                             \
            }                                                                 \
        }                                                                     \
        _Pragma("unroll")                                                     \
        for (int k = 0; k < 2; ++k) {                                         \
            const float mu1 = am12[k].x, mu2 = am12[k].y;                     \
            const float mu1sq = mu1 * mu1, mu2sq = mu2 * mu2;                 \
            const float mu12 = mu1 * mu2;                                     \
            const float sig1 = aqq[k].x - mu1sq;                              \
            const float sig2 = aqq[k].y - mu2sq;                              \
            const float sig12 = asx[k] - mu12;                                \
            const float num = (2.f * mu12 + C1v) * (2.f * sig12 + C2v);       \
            const float den = (mu1sq + mu2sq + C1v) * (sig1 + sig2 + C2v);    \
            float r = __builtin_amdgcn_rcpf(den);                             \
            r = r * (2.f - den * r);             /* Newton -> ~fp32 exact */  \
            lsum += num * r;                                                  \
        }                                                                     \
    }

__global__ __launch_bounds__(256, 8) void ssim_main(
    const float* __restrict__ img1, const float* __restrict__ img2,
    const float* __restrict__ window, float* __restrict__ partial)
{
    __shared__ f4 vv4[HROWS * S4];       // 11520 B
    __shared__ float vsx[HROWS * SX];    //  2880 B -> 14.5 KB total
    __shared__ float g[KW];
    __shared__ float wsum[4];

    const int t = threadIdx.x;

    // Separable 1D Gaussian = row-sums of the 2D window (columns sum to 1).
    if (t < KW) {
        float s = 0.f;
        for (int j = 0; j < KW; ++j) s += window[(t * KW + j) * 3];
        g[t] = s;
    }
    __syncthreads();

    float wg[KW];
#pragma unroll
    for (int j = 0; j < KW; ++j) wg[j] = g[j];   // broadcast: conflict-free

    const float C1v = 0.0001f;
    const float C2v = 0.0009f;

    const int plane = blockIdx.z;
    const size_t base = (size_t)plane * IMH * IMW;
    const int ix0 = blockIdx.x * TW - PAD;
    const int iy0 = blockIdx.y * TH - PAD;

    const bool interior = (ix0 >= 0) && (ix0 + ICOLS <= IMW) &&
                          (iy0 >= 0) && (iy0 + TH + KW - 1 <= IMH);

    float lsum = 0.f;

    // ---- Half 0 ----
    if (interior) { PHASE_A(false, 0) } else { PHASE_A(true, 0) }
    __syncthreads();
    PHASE_B(0)
    __syncthreads();
    // ---- Half 1 ----
    if (interior) { PHASE_A(false, 1) } else { PHASE_A(true, 1) }
    __syncthreads();
    PHASE_B(1)

    // ---- Reduction: wave shuffle -> cross-wave LDS -> per-block store.
#pragma unroll
    for (int off = 32; off > 0; off >>= 1) lsum += __shfl_down(lsum, off, 64);
    if ((t & 63) == 0) wsum[t >> 6] = lsum;
    __syncthreads();
    if (t == 0) {
        unsigned bid = (blockIdx.z * gridDim.y + blockIdx.y) * gridDim.x
                     + blockIdx.x;
        partial[bid] = wsum[0] + wsum[1] + wsum[2] + wsum[3];
    }
}

__global__ __launch_bounds__(1024) void ssim_reduce(
    const float* __restrict__ partial, float* __restrict__ out, double inv_n)
{
    __shared__ double dsum[16];
    const int t = threadIdx.x;
    double s = 0.0;
    for (int i = t; i < NBLK; i += 1024) s += (double)partial[i];
#pragma unroll
    for (int off = 32; off > 0; off >>= 1) s += __shfl_down(s, off, 64);
    if ((t & 63) == 0) dsum[t >> 6] = s;
    __syncthreads();
    if (t == 0) {
        double tot = 0.0;
#pragma unroll
        for (int w = 0; w < 16; ++w) tot += dsum[w];
        out[0] = (float)(tot * inv_n);
    }
}

extern "C" void kernel_launch(void* const* d_in, const int* in_sizes, int n_in,
                              void* d_out, int out_size, void* d_ws, size_t ws_size,
                              hipStream_t stream) {
    const float* img1   = (const float*)d_in[0];
    const float* img2   = (const float*)d_in[1];
    const float* window = (const float*)d_in[2];
    float* out = (float*)d_out;
    float* partial = (float*)d_ws;               // 12288 floats = 48 KB

    const int nplanes = in_sizes[0] / (IMH * IMW);   // 48
    const long long total = (long long)in_sizes[0];

    dim3 grid(IMW / TW, IMH / TH, nplanes);      // 16 x 16 x 48 = 12288
    ssim_main<<<grid, 256, 0, stream>>>(img1, img2, window, partial);
    ssim_reduce<<<1, 1024, 0, stream>>>(partial, out, 1.0 / (double)total);
}

// Round 9
// 170.881 us; speedup vs baseline: 2.7692x; 2.7692x over previous
//
#include <hip/hip_runtime.h>

#define KW 11
#define PAD 5
#define TW 32
#define TH 32
#define HROWS 16           // rows per half-tile (phase B row r needs only vv row r)
#define ICOLS 42           // input col span incl. halo (TW + KW - 1)
#define S4 45              // float4-plane row stride (ODD; 180 mod 32 = 20 -> 8 distinct b128 groups)
#define SX 45              // sx-plane row stride
#define IMH 512
#define IMW 512
#define NBLK 12288         // 16 x 16 x 48

typedef float f2 __attribute__((ext_vector_type(2)));
typedef float f4 __attribute__((ext_vector_type(4)));

// LDS layout (per 16-row half): vv4[row*S4 + col] = (mu1,mu2,q11,q22) float4
//                               vsx[row*SX + col] = x1*x2 moment (f32)
// Half-split: A0 -> bar -> B0 -> bar -> A1 -> bar -> B1. LDS = 14.5 KB.
//
// R6 lesson: hoisting all phase-A loads into distinct regs (MLP) is THE win
// (199 -> 90 us). R8 lesson: __launch_bounds__(256,8) DEMANDS 8 waves/SIMD
// -> compiler caps VGPR at 32 -> the 28 hoisted loads spill (WRITE 634 MB,
// 382 us). Fix: cap-only (256,4); get under the 64-VGPR tier by (a) weights
// in SGPRs via readfirstlane (wave-uniform, VALU reads SGPR operand free),
// (b) phase-B LDS reads batched 2x6 (LDS latency is cheap; HBM is not).

#define PHASE_A(EDGE_, H_)                                                    \
    if (t < ICOLS * 4) {                                                      \
        const int c  = t % ICOLS;                                             \
        const int rg = t / ICOLS;            /* 0..3 */                       \
        const int r0 = rg * 4;               /* local row base in half */     \
        const int gr0 = iy0 + (H_) * HROWS + r0;                              \
        const int gc = ix0 + c;                                               \
        float a1[14], a2[14];                                                 \
        if (EDGE_) {                                                          \
            const bool cok = (gc >= 0) && (gc < IMW);                         \
            _Pragma("unroll")                                                 \
            for (int i = 0; i < 14; ++i) {                                    \
                const int gr = gr0 + i;                                       \
                const bool ok = cok && (gr >= 0) && (gr < IMH);               \
                const size_t o = base + (size_t)(ok ? gr : 0) * IMW           \
                               + (ok ? gc : 0);                               \
                a1[i] = ok ? img1[o] : 0.f;                                   \
                a2[i] = ok ? img2[o] : 0.f;                                   \
            }                                                                 \
        } else {                                                              \
            /* 28 scalar loads issued back-to-back into distinct regs */      \
            _Pragma("unroll")                                                 \
            for (int i = 0; i < 14; ++i) {                                    \
                const size_t o = base + (size_t)(gr0 + i) * IMW + gc;         \
                a1[i] = img1[o];                                              \
                a2[i] = img2[o];                                              \
            }                                                                 \
        }                                                                     \
        f2 m12[4]  = {{0,0},{0,0},{0,0},{0,0}};                               \
        f2 qq[4]   = {{0,0},{0,0},{0,0},{0,0}};                               \
        float sx[4] = {0, 0, 0, 0};                                           \
        _Pragma("unroll")                                                     \
        for (int i = 0; i < 14; ++i) {                                        \
            f2 x12; x12.x = a1[i]; x12.y = a2[i];                             \
            const f2 sq = x12 * x12;                                          \
            const float sxy = a1[i] * a2[i];                                  \
            _Pragma("unroll")                                                 \
            for (int k = 0; k < 4; ++k) {                                     \
                const int j = i - k;                                          \
                if (j >= 0 && j < KW) {                                       \
                    const float w = wg[j];   /* SGPR operand */               \
                    const f2 w2 = {w, w};                                     \
                    m12[k] += w2 * x12;          /* v_pk_fma_f32 */           \
                    qq[k]  += w2 * sq;           /* v_pk_fma_f32 */           \
                    sx[k]  += w * sxy;                                        \
                }                                                             \
            }                                                                 \
        }                                                                     \
        _Pragma("unroll")                                                     \
        for (int k = 0; k < 4; ++k) {                                         \
            f4 v;                                                             \
            v.x = m12[k].x; v.y = m12[k].y;                                   \
            v.z = qq[k].x;  v.w = qq[k].y;                                    \
            vv4[(r0 + k) * S4 + c] = v;          /* ds_write_b128 */          \
            vsx[(r0 + k) * SX + c] = sx[k];      /* ds_write_b32  */          \
        }                                                                     \
    }

// Phase B: 2 output cols per thread, 16 rows x 16 col-pairs = 256 tasks.
// Output col X=2cp+k uses local cols 2cp+k+j (j=0..10) -> cc = 0..11,
// read in two 6-col batches (30 regs/batch) to stay under the 64-VGPR tier.
#define PHASE_B(H_)                                                           \
    {                                                                         \
        const int row = t >> 4;              /* 0..15 */                      \
        const int cp  = t & 15;              /* col pair 0..15 */             \
        const f4* __restrict__ p4 = &vv4[row * S4 + cp * 2];                  \
        const float* __restrict__ px = &vsx[row * SX + cp * 2];               \
        f2 am12[2] = {{0,0},{0,0}};                                           \
        f2 aqq[2]  = {{0,0},{0,0}};                                           \
        float asx[2] = {0, 0};                                                \
        _Pragma("unroll")                                                     \
        for (int b = 0; b < 2; ++b) {                                         \
            f4 v[6]; float vx[6];                                             \
            _Pragma("unroll")                                                 \
            for (int cc = 0; cc < 6; ++cc) {                                  \
                v[cc]  = p4[b * 6 + cc];                                      \
                vx[cc] = px[b * 6 + cc];                                      \
            }                                                                 \
            _Pragma("unroll")                                                 \
            for (int cc = 0; cc < 6; ++cc) {                                  \
                const int cg = b * 6 + cc;                                    \
                f2 v12; v12.x = v[cc].x; v12.y = v[cc].y;                     \
                f2 vqq; vqq.x = v[cc].z; vqq.y = v[cc].w;                     \
                _Pragma("unroll")                                             \
                for (int k = 0; k < 2; ++k) {                                 \
                    const int j = cg - k;                                     \
                    if (j >= 0 && j < KW) {                                   \
                        const float w = wg[j];                                \
                        const f2 w2 = {w, w};                                 \
                        am12[k] += w2 * v12;                                  \
                        aqq[k]  += w2 * vqq;                                  \
                        asx[k]  += w * vx[cc];                                \
                    }                                                         \
                }                                                             \
            }                                                                 \
        }                                                                     \
        _Pragma("unroll")                                                     \
        for (int k = 0; k < 2; ++k) {                                         \
            const float mu1 = am12[k].x, mu2 = am12[k].y;                     \
            const float mu1sq = mu1 * mu1, mu2sq = mu2 * mu2;                 \
            const float mu12 = mu1 * mu2;                                     \
            const float sig1 = aqq[k].x - mu1sq;                              \
            const float sig2 = aqq[k].y - mu2sq;                              \
            const float sig12 = asx[k] - mu12;                                \
            const float num = (2.f * mu12 + C1v) * (2.f * sig12 + C2v);       \
            const float den = (mu1sq + mu2sq + C1v) * (sig1 + sig2 + C2v);    \
            float r = __builtin_amdgcn_rcpf(den);                             \
            r = r * (2.f - den * r);             /* Newton -> ~fp32 exact */  \
            lsum += num * r;                                                  \
        }                                                                     \
    }

__global__ __launch_bounds__(256, 4) void ssim_main(
    const float* __restrict__ img1, const float* __restrict__ img2,
    const float* __restrict__ window, float* __restrict__ partial)
{
    __shared__ f4 vv4[HROWS * S4];       // 11520 B
    __shared__ float vsx[HROWS * SX];    //  2880 B -> 14.5 KB total
    __shared__ float g[KW];
    __shared__ float wsum[4];

    const int t = threadIdx.x;

    // Separable 1D Gaussian = row-sums of the 2D window (columns sum to 1).
    if (t < KW) {
        float s = 0.f;
        for (int j = 0; j < KW; ++j) s += window[(t * KW + j) * 3];
        g[t] = s;
    }
    __syncthreads();

    // Weights are wave-uniform -> pin to SGPRs (frees 11 VGPRs; VALU reads
    // one SGPR operand per instruction for free).
    float wg[KW];
#pragma unroll
    for (int j = 0; j < KW; ++j) {
        const int bi = __builtin_amdgcn_readfirstlane(__float_as_int(g[j]));
        wg[j] = __int_as_float(bi);
    }

    const float C1v = 0.0001f;
    const float C2v = 0.0009f;

    const int plane = blockIdx.z;
    const size_t base = (size_t)plane * IMH * IMW;
    const int ix0 = blockIdx.x * TW - PAD;
    const int iy0 = blockIdx.y * TH - PAD;

    const bool interior = (ix0 >= 0) && (ix0 + ICOLS <= IMW) &&
                          (iy0 >= 0) && (iy0 + TH + KW - 1 <= IMH);

    float lsum = 0.f;

    // ---- Half 0 ----
    if (interior) { PHASE_A(false, 0) } else { PHASE_A(true, 0) }
    __syncthreads();
    PHASE_B(0)
    __syncthreads();
    // ---- Half 1 ----
    if (interior) { PHASE_A(false, 1) } else { PHASE_A(true, 1) }
    __syncthreads();
    PHASE_B(1)

    // ---- Reduction: wave shuffle -> cross-wave LDS -> per-block store.
#pragma unroll
    for (int off = 32; off > 0; off >>= 1) lsum += __shfl_down(lsum, off, 64);
    if ((t & 63) == 0) wsum[t >> 6] = lsum;
    __syncthreads();
    if (t == 0) {
        unsigned bid = (blockIdx.z * gridDim.y + blockIdx.y) * gridDim.x
                     + blockIdx.x;
        partial[bid] = wsum[0] + wsum[1] + wsum[2] + wsum[3];
    }
}

__global__ __launch_bounds__(1024) void ssim_reduce(
    const float* __restrict__ partial, float* __restrict__ out, double inv_n)
{
    __shared__ double dsum[16];
    const int t = threadIdx.x;
    double s = 0.0;
    for (int i = t; i < NBLK; i += 1024) s += (double)partial[i];
#pragma unroll
    for (int off = 32; off > 0; off >>= 1) s += __shfl_down(s, off, 64);
    if ((t & 63) == 0) dsum[t >> 6] = s;
    __syncthreads();
    if (t == 0) {
        double tot = 0.0;
#pragma unroll
        for (int w = 0; w < 16; ++w) tot += dsum[w];
        out[0] = (float)(tot * inv_n);
    }
}

extern "C" void kernel_launch(void* const* d_in, const int* in_sizes, int n_in,
                              void* d_out, int out_size, void* d_ws, size_t ws_size,
                              hipStream_t stream) {
    const float* img1   = (const float*)d_in[0];
    const float* img2   = (const float*)d_in[1];
    const float* window = (const float*)d_in[2];
    float* out = (float*)d_out;
    float* partial = (float*)d_ws;               // 12288 floats = 48 KB

    const int nplanes = in_sizes[0] / (IMH * IMW);   // 48
    const long long total = (long long)in_sizes[0];

    dim3 grid(IMW / TW, IMH / TH, nplanes);      // 16 x 16 x 48 = 12288
    ssim_main<<<grid, 256, 0, stream>>>(img1, img2, window, partial);
    ssim_reduce<<<1, 1024, 0, stream>>>(partial, out, 1.0 / (double)total);
}

// Round 10
// 170.346 us; speedup vs baseline: 2.7779x; 1.0031x over previous
//
#include <hip/hip_runtime.h>

#define KW 11
#define PAD 5
#define TW 32
#define TH 32
#define HROWS 16           // rows per half-tile (phase B row r needs only vv row r)
#define ICOLS 42           // input col span incl. halo (TW + KW - 1)
#define S4 45              // float4-plane row stride (ODD; 180 mod 32 = 20 -> 8 distinct b128 groups)
#define SX 45              // sx-plane row stride
#define IMH 512
#define IMW 512
#define NBLK 12288         // 16 x 16 x 48

typedef float f2 __attribute__((ext_vector_type(2)));
typedef float f4 __attribute__((ext_vector_type(4)));

// Schedule (T14 async-split): A0.load -> A0.conv | bar | A1.load-issue -> B0
// | bar | A1.conv | bar | B1. The next half's 28 HBM loads issue BEFORE the
// preceding B phase, so ~900-cyc HBM latency hides under B's VALU work
// instead of sitting exposed on the critical path. A0's loads issue at the
// very top, hidden under window-prep + barrier.
//
// R6 lesson: hoisted loads (MLP) are THE lever (199 -> 90 us).
// R8 lesson: never DEMAND occupancy via launch_bounds (min-waves 8 capped
// VGPR at 32 -> 634 MB spill). Cap-only (256,4) = 128-VGPR tier.
// R9 lesson: half-split LDS (14.5 KB) + SGPR weights + batched B reads ->
// VGPR 40, occ 54%, 82 us. WRITE_SIZE above ~0.4 MB = spill alarm.
// R5 lesson (risk here): compiler may SINK prefetch loads to cut pressure;
// success signal for this round is VGPR rising to ~70-110.

#define A_LOAD(EDGE_, H_)                                                     \
    if (aon) {                                                                \
        const int gr0 = iy0 + (H_) * HROWS + ar0;                             \
        if (EDGE_) {                                                          \
            const bool cok = (agc >= 0) && (agc < IMW);                       \
            _Pragma("unroll")                                                 \
            for (int i = 0; i < 14; ++i) {                                    \
                const int gr = gr0 + i;                                       \
                const bool ok = cok && (gr >= 0) && (gr < IMH);               \
                const size_t o = base + (size_t)(ok ? gr : 0) * IMW           \
                               + (ok ? agc : 0);                              \
                p1[i] = ok ? img1[o] : 0.f;                                   \
                p2[i] = ok ? img2[o] : 0.f;                                   \
            }                                                                 \
        } else {                                                              \
            /* 28 scalar loads back-to-back into distinct regs (MLP) */       \
            _Pragma("unroll")                                                 \
            for (int i = 0; i < 14; ++i) {                                    \
                const size_t o = base + (size_t)(gr0 + i) * IMW + agc;        \
                p1[i] = img1[o];                                              \
                p2[i] = img2[o];                                              \
            }                                                                 \
        }                                                                     \
    }

#define A_CONV(H_)                                                            \
    if (aon) {                                                                \
        f2 m12[4]  = {{0,0},{0,0},{0,0},{0,0}};                               \
        f2 qq[4]   = {{0,0},{0,0},{0,0},{0,0}};                               \
        float sx[4] = {0, 0, 0, 0};                                           \
        _Pragma("unroll")                                                     \
        for (int i = 0; i < 14; ++i) {                                        \
            f2 x12; x12.x = p1[i]; x12.y = p2[i];                             \
            const f2 sq = x12 * x12;                                          \
            const float sxy = p1[i] * p2[i];                                  \
            _Pragma("unroll")                                                 \
            for (int k = 0; k < 4; ++k) {                                     \
                const int j = i - k;                                          \
                if (j >= 0 && j < KW) {                                       \
                    const float w = wg[j];   /* SGPR operand */               \
                    const f2 w2 = {w, w};                                     \
                    m12[k] += w2 * x12;          /* v_pk_fma_f32 */           \
                    qq[k]  += w2 * sq;           /* v_pk_fma_f32 */           \
                    sx[k]  += w * sxy;                                        \
                }                                                             \
            }                                                                 \
        }                                                                     \
        _Pragma("unroll")                                                     \
        for (int k = 0; k < 4; ++k) {                                         \
            f4 v;                                                             \
            v.x = m12[k].x; v.y = m12[k].y;                                   \
            v.z = qq[k].x;  v.w = qq[k].y;                                    \
            vv4[(ar0 + k) * S4 + ac] = v;        /* ds_write_b128 */          \
            vsx[(ar0 + k) * SX + ac] = sx[k];    /* ds_write_b32  */          \
        }                                                                     \
    }

// Phase B: 2 output cols per thread, 16 rows x 16 col-pairs = 256 tasks.
// Output col X=2cp+k uses local cols 2cp+k+j (j=0..10) -> cc = 0..11,
// read in three 4-col batches (20 regs/batch) to leave room for the
// prefetched p1/p2 (28 regs) living across B0.
#define PHASE_B(H_)                                                           \
    {                                                                         \
        const int row = t >> 4;              /* 0..15 */                      \
        const int cp  = t & 15;              /* col pair 0..15 */             \
        const f4* __restrict__ p4 = &vv4[row * S4 + cp * 2];                  \
        const float* __restrict__ px = &vsx[row * SX + cp * 2];               \
        f2 am12[2] = {{0,0},{0,0}};                                           \
        f2 aqq[2]  = {{0,0},{0,0}};                                           \
        float asx[2] = {0, 0};                                                \
        _Pragma("unroll")                                                     \
        for (int b = 0; b < 3; ++b) {                                         \
            f4 v[4]; float vx[4];                                             \
            _Pragma("unroll")                                                 \
            for (int cc = 0; cc < 4; ++cc) {                                  \
                v[cc]  = p4[b * 4 + cc];                                      \
                vx[cc] = px[b * 4 + cc];                                      \
            }                                                                 \
            _Pragma("unroll")                                                 \
            for (int cc = 0; cc < 4; ++cc) {                                  \
                const int cg = b * 4 + cc;                                    \
                f2 v12; v12.x = v[cc].x; v12.y = v[cc].y;                     \
                f2 vqq; vqq.x = v[cc].z; vqq.y = v[cc].w;                     \
                _Pragma("unroll")                                             \
                for (int k = 0; k < 2; ++k) {                                 \
                    const int j = cg - k;                                     \
                    if (j >= 0 && j < KW) {                                   \
                        const float w = wg[j];                                \
                        const f2 w2 = {w, w};                                 \
                        am12[k] += w2 * v12;                                  \
                        aqq[k]  += w2 * vqq;                                  \
                        asx[k]  += w * vx[cc];                                \
                    }                                                         \
                }                                                             \
            }                                                                 \
        }                                                                     \
        _Pragma("unroll")                                                     \
        for (int k = 0; k < 2; ++k) {                                         \
            const float mu1 = am12[k].x, mu2 = am12[k].y;                     \
            const float mu1sq = mu1 * mu1, mu2sq = mu2 * mu2;                 \
            const float mu12 = mu1 * mu2;                                     \
            const float sig1 = aqq[k].x - mu1sq;                              \
            const float sig2 = aqq[k].y - mu2sq;                              \
            const float sig12 = asx[k] - mu12;                                \
            const float num = (2.f * mu12 + C1v) * (2.f * sig12 + C2v);       \
            const float den = (mu1sq + mu2sq + C1v) * (sig1 + sig2 + C2v);    \
            float r = __builtin_amdgcn_rcpf(den);                             \
            r = r * (2.f - den * r);             /* Newton -> ~fp32 exact */  \
            lsum += num * r;                                                  \
        }                                                                     \
    }

__global__ __launch_bounds__(256, 4) void ssim_main(
    const float* __restrict__ img1, const float* __restrict__ img2,
    const float* __restrict__ window, float* __restrict__ partial)
{
    __shared__ f4 vv4[HROWS * S4];       // 11520 B
    __shared__ float vsx[HROWS * SX];    //  2880 B -> 14.5 KB total
    __shared__ float g[KW];
    __shared__ float wsum[4];

    const int t = threadIdx.x;

    const int plane = blockIdx.z;
    const size_t base = (size_t)plane * IMH * IMW;
    const int ix0 = blockIdx.x * TW - PAD;
    const int iy0 = blockIdx.y * TH - PAD;

    const bool aon = t < ICOLS * 4;               // 168 phase-A threads
    const int ac  = t % ICOLS;                    // col (valid when aon)
    const int ar0 = (t / ICOLS) * 4;              // local row base in half
    const int agc = ix0 + ac;

    const bool interior = (ix0 >= 0) && (ix0 + ICOLS <= IMW) &&
                          (iy0 >= 0) && (iy0 + TH + KW - 1 <= IMH);

    float p1[14], p2[14];                         // A-phase prefetch regs

    // Issue half-0 loads FIRST: latency hides under window prep + barrier.
    if (interior) { A_LOAD(false, 0) } else { A_LOAD(true, 0) }

    // Separable 1D Gaussian = row-sums of the 2D window (columns sum to 1).
    if (t < KW) {
        float s = 0.f;
        for (int j = 0; j < KW; ++j) s += window[(t * KW + j) * 3];
        g[t] = s;
    }
    __syncthreads();

    // Weights wave-uniform -> SGPRs (VALU reads one SGPR operand free).
    float wg[KW];
#pragma unroll
    for (int j = 0; j < KW; ++j) {
        const int bi = __builtin_amdgcn_readfirstlane(__float_as_int(g[j]));
        wg[j] = __int_as_float(bi);
    }

    const float C1v = 0.0001f;
    const float C2v = 0.0009f;
    float lsum = 0.f;

    // ---- Half 0 compute ----
    A_CONV(0)
    __syncthreads();

    // ---- Prefetch half-1 loads, then run B0 over them (T14) ----
    if (interior) { A_LOAD(false, 1) } else { A_LOAD(true, 1) }
    PHASE_B(0)
    __syncthreads();

    // ---- Half 1 compute ----
    A_CONV(1)
    __syncthreads();
    PHASE_B(1)

    // ---- Reduction: wave shuffle -> cross-wave LDS -> per-block store.
#pragma unroll
    for (int off = 32; off > 0; off >>= 1) lsum += __shfl_down(lsum, off, 64);
    if ((t & 63) == 0) wsum[t >> 6] = lsum;
    __syncthreads();
    if (t == 0) {
        unsigned bid = (blockIdx.z * gridDim.y + blockIdx.y) * gridDim.x
                     + blockIdx.x;
        partial[bid] = wsum[0] + wsum[1] + wsum[2] + wsum[3];
    }
}

__global__ __launch_bounds__(1024) void ssim_reduce(
    const float* __restrict__ partial, float* __restrict__ out, double inv_n)
{
    __shared__ double dsum[16];
    const int t = threadIdx.x;
    double s = 0.0;
    for (int i = t; i < NBLK; i += 1024) s += (double)partial[i];
#pragma unroll
    for (int off = 32; off > 0; off >>= 1) s += __shfl_down(s, off, 64);
    if ((t & 63) == 0) dsum[t >> 6] = s;
    __syncthreads();
    if (t == 0) {
        double tot = 0.0;
#pragma unroll
        for (int w = 0; w < 16; ++w) tot += dsum[w];
        out[0] = (float)(tot * inv_n);
    }
}

extern "C" void kernel_launch(void* const* d_in, const int* in_sizes, int n_in,
                              void* d_out, int out_size, void* d_ws, size_t ws_size,
                              hipStream_t stream) {
    const float* img1   = (const float*)d_in[0];
    const float* img2   = (const float*)d_in[1];
    const float* window = (const float*)d_in[2];
    float* out = (float*)d_out;
    float* partial = (float*)d_ws;               // 12288 floats = 48 KB

    const int nplanes = in_sizes[0] / (IMH * IMW);   // 48
    const long long total = (long long)in_sizes[0];

    dim3 grid(IMW / TW, IMH / TH, nplanes);      // 16 x 16 x 48 = 12288
    ssim_main<<<grid, 256, 0, stream>>>(img1, img2, window, partial);
    ssim_reduce<<<1, 1024, 0, stream>>>(partial, out, 1.0 / (double)total);
}

// Round 11
// 162.307 us; speedup vs baseline: 2.9154x; 1.0495x over previous
//
#include <hip/hip_runtime.h>

#define KW 11
#define PAD 5
#define TW 64              // tile width (R11: 32 -> 64, halo overhead 1.31x -> 1.16x)
#define TH 32
#define HROWS 16           // rows per half-tile (phase B row r needs only vv row r)
#define ICOLS 74           // input col span incl. halo (TW + KW - 1)
#define S4 77              // float4-plane row stride (ODD -> b128 rows spread banks)
#define SX 77              // sx-plane row stride
#define IMH 512
#define IMW 512
#define NBLK 6144          // 8 x 16 x 48

typedef float f2 __attribute__((ext_vector_type(2)));
typedef float f4 __attribute__((ext_vector_type(4)));

// LDS (per 16-row half): vv4[row*S4+col] = (mu1,mu2,q11,q22) f4; vsx = x1*x2.
// Schedule: A0.load -> prep | bar | A0.conv | bar | A1.load -> B0 | bar |
//           A1.conv | bar | B1.  512 threads, 8 waves, 4 blocks/CU (LDS 24.7KB).
//
// R6 lesson: hoisted loads (MLP) are THE lever (199 -> 90 us).
// R8 lesson: never DEMAND occupancy via launch_bounds min-waves (VGPR cap 32
// -> 634 MB spill, 382 us). Cap-only bounds; WRITE_SIZE > ~1 MB = spill alarm.
// R9 lesson: half-split + SGPR weights + batched B reads -> 82 us, occ 54%.
// R10 lesson: compiler SINKS prefetch loads (VGPR 40->36); T14 split gave ~0.
//   Asm-anchoring can't fix it (anchor forces the WAIT early, not the issue).
// R11: attack structural overheads instead: halo (42/32 -> 74/64) and
//   per-block fixed cost (12288 -> 6144 blocks).

#define A_LOAD(EDGE_, H_)                                                     \
    if (aon) {                                                                \
        const int gr0 = iy0 + (H_) * HROWS + ar0;                             \
        if (EDGE_) {                                                          \
            const bool cok = (agc >= 0) && (agc < IMW);                       \
            _Pragma("unroll")                                                 \
            for (int i = 0; i < 14; ++i) {                                    \
                const int gr = gr0 + i;                                       \
                const bool ok = cok && (gr >= 0) && (gr < IMH);               \
                const size_t o = base + (size_t)(ok ? gr : 0) * IMW           \
                               + (ok ? agc : 0);                              \
                p1[i] = ok ? img1[o] : 0.f;                                   \
                p2[i] = ok ? img2[o] : 0.f;                                   \
            }                                                                 \
        } else {                                                              \
            /* 28 scalar loads back-to-back into distinct regs (MLP) */       \
            _Pragma("unroll")                                                 \
            for (int i = 0; i < 14; ++i) {                                    \
                const size_t o = base + (size_t)(gr0 + i) * IMW + agc;        \
                p1[i] = img1[o];                                              \
                p2[i] = img2[o];                                              \
            }                                                                 \
        }                                                                     \
    }

#define A_CONV(H_)                                                            \
    if (aon) {                                                                \
        f2 m12[4]  = {{0,0},{0,0},{0,0},{0,0}};                               \
        f2 qq[4]   = {{0,0},{0,0},{0,0},{0,0}};                               \
        float sx[4] = {0, 0, 0, 0};                                           \
        _Pragma("unroll")                                                     \
        for (int i = 0; i < 14; ++i) {                                        \
            f2 x12; x12.x = p1[i]; x12.y = p2[i];                             \
            const f2 sq = x12 * x12;                                          \
            const float sxy = p1[i] * p2[i];                                  \
            _Pragma("unroll")                                                 \
            for (int k = 0; k < 4; ++k) {                                     \
                const int j = i - k;                                          \
                if (j >= 0 && j < KW) {                                       \
                    const float w = wg[j];   /* SGPR operand */               \
                    const f2 w2 = {w, w};                                     \
                    m12[k] += w2 * x12;          /* v_pk_fma_f32 */           \
                    qq[k]  += w2 * sq;           /* v_pk_fma_f32 */           \
                    sx[k]  += w * sxy;                                        \
                }                                                             \
            }                                                                 \
        }                                                                     \
        _Pragma("unroll")                                                     \
        for (int k = 0; k < 4; ++k) {                                         \
            f4 v;                                                             \
            v.x = m12[k].x; v.y = m12[k].y;                                   \
            v.z = qq[k].x;  v.w = qq[k].y;                                    \
            vv4[(ar0 + k) * S4 + ac] = v;        /* ds_write_b128 */          \
            vsx[(ar0 + k) * SX + ac] = sx[k];    /* ds_write_b32  */          \
        }                                                                     \
    }

// Phase B: 2 output cols per thread, 16 rows x 32 col-pairs = 512 tasks.
// Output col X=2cp+k uses local cols 2cp+k+j (j=0..10) -> cc = 0..11,
// read in three 4-col batches (20 regs/batch).
#define PHASE_B(H_)                                                           \
    {                                                                         \
        const int row = t >> 5;              /* 0..15 */                      \
        const int cp  = t & 31;              /* col pair 0..31 */             \
        const f4* __restrict__ p4 = &vv4[row * S4 + cp * 2];                  \
        const float* __restrict__ px = &vsx[row * SX + cp * 2];               \
        f2 am12[2] = {{0,0},{0,0}};                                           \
        f2 aqq[2]  = {{0,0},{0,0}};                                           \
        float asx[2] = {0, 0};                                                \
        _Pragma("unroll")                                                     \
        for (int b = 0; b < 3; ++b) {                                         \
            f4 v[4]; float vx[4];                                             \
            _Pragma("unroll")                                                 \
            for (int cc = 0; cc < 4; ++cc) {                                  \
                v[cc]  = p4[b * 4 + cc];                                      \
                vx[cc] = px[b * 4 + cc];                                      \
            }                                                                 \
            _Pragma("unroll")                                                 \
            for (int cc = 0; cc < 4; ++cc) {                                  \
                const int cg = b * 4 + cc;                                    \
                f2 v12; v12.x = v[cc].x; v12.y = v[cc].y;                     \
                f2 vqq; vqq.x = v[cc].z; vqq.y = v[cc].w;                     \
                _Pragma("unroll")                                             \
                for (int k = 0; k < 2; ++k) {                                 \
                    const int j = cg - k;                                     \
                    if (j >= 0 && j < KW) {                                   \
                        const float w = wg[j];                                \
                        const f2 w2 = {w, w};                                 \
                        am12[k] += w2 * v12;                                  \
                        aqq[k]  += w2 * vqq;                                  \
                        asx[k]  += w * vx[cc];                                \
                    }                                                         \
                }                                                             \
            }                                                                 \
        }                                                                     \
        _Pragma("unroll")                                                     \
        for (int k = 0; k < 2; ++k) {                                         \
            const float mu1 = am12[k].x, mu2 = am12[k].y;                     \
            const float mu1sq = mu1 * mu1, mu2sq = mu2 * mu2;                 \
            const float mu12 = mu1 * mu2;                                     \
            const float sig1 = aqq[k].x - mu1sq;                              \
            const float sig2 = aqq[k].y - mu2sq;                              \
            const float sig12 = asx[k] - mu12;                                \
            const float num = (2.f * mu12 + C1v) * (2.f * sig12 + C2v);       \
            const float den = (mu1sq + mu2sq + C1v) * (sig1 + sig2 + C2v);    \
            float r = __builtin_amdgcn_rcpf(den);                             \
            r = r * (2.f - den * r);             /* Newton -> ~fp32 exact */  \
            lsum += num * r;                                                  \
        }                                                                     \
    }

__global__ __launch_bounds__(512, 4) void ssim_main(
    const float* __restrict__ img1, const float* __restrict__ img2,
    const float* __restrict__ window, float* __restrict__ partial)
{
    __shared__ f4 vv4[HROWS * S4];       // 19712 B
    __shared__ float vsx[HROWS * SX];    //  4928 B -> 24.7 KB total
    __shared__ float g[KW];
    __shared__ float wsum[8];

    const int t = threadIdx.x;

    const int plane = blockIdx.z;
    const size_t base = (size_t)plane * IMH * IMW;
    const int ix0 = blockIdx.x * TW - PAD;
    const int iy0 = blockIdx.y * TH - PAD;

    const bool aon = t < ICOLS * 4;               // 296 phase-A threads
    const int ac  = t % ICOLS;                    // col (valid when aon)
    const int ar0 = (t / ICOLS) * 4;              // local row base in half
    const int agc = ix0 + ac;

    const bool interior = (ix0 >= 0) && (ix0 + ICOLS <= IMW) &&
                          (iy0 >= 0) && (iy0 + TH + KW - 1 <= IMH);

    float p1[14], p2[14];                         // A-phase load regs

    // Issue half-0 loads first: latency hides under window prep + barrier.
    if (interior) { A_LOAD(false, 0) } else { A_LOAD(true, 0) }

    // Separable 1D Gaussian = row-sums of the 2D window (columns sum to 1).
    if (t < KW) {
        float s = 0.f;
        for (int j = 0; j < KW; ++j) s += window[(t * KW + j) * 3];
        g[t] = s;
    }
    __syncthreads();

    // Weights wave-uniform -> SGPRs (VALU reads one SGPR operand free).
    float wg[KW];
#pragma unroll
    for (int j = 0; j < KW; ++j) {
        const int bi = __builtin_amdgcn_readfirstlane(__float_as_int(g[j]));
        wg[j] = __int_as_float(bi);
    }

    const float C1v = 0.0001f;
    const float C2v = 0.0009f;
    float lsum = 0.f;

    // ---- Half 0 compute ----
    A_CONV(0)
    __syncthreads();

    // ---- Issue half-1 loads, then run B0 (compiler may still sink; ~free) --
    if (interior) { A_LOAD(false, 1) } else { A_LOAD(true, 1) }
    PHASE_B(0)
    __syncthreads();

    // ---- Half 1 compute ----
    A_CONV(1)
    __syncthreads();
    PHASE_B(1)

    // ---- Reduction: wave shuffle -> cross-wave LDS -> per-block store.
#pragma unroll
    for (int off = 32; off > 0; off >>= 1) lsum += __shfl_down(lsum, off, 64);
    if ((t & 63) == 0) wsum[t >> 6] = lsum;
    __syncthreads();
    if (t == 0) {
        float bs = 0.f;
#pragma unroll
        for (int w = 0; w < 8; ++w) bs += wsum[w];
        unsigned bid = (blockIdx.z * gridDim.y + blockIdx.y) * gridDim.x
                     + blockIdx.x;
        partial[bid] = bs;
    }
}

__global__ __launch_bounds__(1024) void ssim_reduce(
    const float* __restrict__ partial, float* __restrict__ out, double inv_n)
{
    __shared__ double dsum[16];
    const int t = threadIdx.x;
    double s = 0.0;
    for (int i = t; i < NBLK; i += 1024) s += (double)partial[i];
#pragma unroll
    for (int off = 32; off > 0; off >>= 1) s += __shfl_down(s, off, 64);
    if ((t & 63) == 0) dsum[t >> 6] = s;
    __syncthreads();
    if (t == 0) {
        double tot = 0.0;
#pragma unroll
        for (int w = 0; w < 16; ++w) tot += dsum[w];
        out[0] = (float)(tot * inv_n);
    }
}

extern "C" void kernel_launch(void* const* d_in, const int* in_sizes, int n_in,
                              void* d_out, int out_size, void* d_ws, size_t ws_size,
                              hipStream_t stream) {
    const float* img1   = (const float*)d_in[0];
    const float* img2   = (const float*)d_in[1];
    const float* window = (const float*)d_in[2];
    float* out = (float*)d_out;
    float* partial = (float*)d_ws;               // 6144 floats = 24 KB

    const int nplanes = in_sizes[0] / (IMH * IMW);   // 48
    const long long total = (long long)in_sizes[0];

    dim3 grid(IMW / TW, IMH / TH, nplanes);      // 8 x 16 x 48 = 6144
    ssim_main<<<grid, 512, 0, stream>>>(img1, img2, window, partial);
    ssim_reduce<<<1, 1024, 0, stream>>>(partial, out, 1.0 / (double)total);
}

// Round 12
// 161.262 us; speedup vs baseline: 2.9343x; 1.0065x over previous
//
#include <hip/hip_runtime.h>

#define KW 11
#define PAD 5
#define TW 64              // tile width (halo overhead 74/64 = 1.16x)
#define TH 32
#define HROWS 16           // rows per half-tile (phase B row r needs only vv row r)
#define ICOLS 74           // input col span incl. halo (TW + KW - 1)
#define S4 77              // float4-plane row stride (308 words = 20 mod 32)
#define SX 77              // sx-plane row stride
#define IMH 512
#define IMW 512
#define NBLK 6144          // 8 x 16 x 48

typedef float f2 __attribute__((ext_vector_type(2)));
typedef float f4 __attribute__((ext_vector_type(4)));

// LDS (per 16-row half): vv4[row*S4+col] = (mu1,mu2,q11,q22) f4; vsx = x1*x2.
// Schedule: A0.load -> prep | bar | A0.conv | bar | A1.load -> B0 | bar |
//           A1.conv | bar | B1.  512 threads, 8 waves, 4 blocks/CU.
//
// R6: hoisted loads (MLP) are THE lever. R8: never DEMAND occupancy via
// launch_bounds min-waves (spill disaster). R9: SGPR weights + batched reads.
// R10: compiler sinks prefetch loads; T14 split ~0 here. R11: TW=64 cut
// FETCH to 92 MB (< ideal; L3 absorbs halo) BUT row=t>>5 in phase B put all
// 32 lanes of a half-wave on ONE row -> b128 starts only at {0,8,16,24} ->
// 2x bank conflict (7.37M, ~15% of time).
// R12 fix: row=t&15 / cp=t>>4 -> start bank (20*row + 8*cp) mod 32 spreads
// 4 words/bank (min) for both 16- and 32-lane groupings. Plus packed-weight
// pairs wp[j]={w[j],w[j-1]} turn the sx moment into v_pk_fma too
// (A: 12 vs 14 VALU/iter; B: 5 vs 6 per col).

#define A_LOAD(EDGE_, H_)                                                     \
    if (aon) {                                                                \
        const int gr0 = iy0 + (H_) * HROWS + ar0;                             \
        if (EDGE_) {                                                          \
            const bool cok = (agc >= 0) && (agc < IMW);                       \
            _Pragma("unroll")                                                 \
            for (int i = 0; i < 14; ++i) {                                    \
                const int gr = gr0 + i;                                       \
                const bool ok = cok && (gr >= 0) && (gr < IMH);               \
                const size_t o = base + (size_t)(ok ? gr : 0) * IMW           \
                               + (ok ? agc : 0);                              \
                p1[i] = ok ? img1[o] : 0.f;                                   \
                p2[i] = ok ? img2[o] : 0.f;                                   \
            }                                                                 \
        } else {                                                              \
            /* 28 scalar loads back-to-back into distinct regs (MLP) */       \
            _Pragma("unroll")                                                 \
            for (int i = 0; i < 14; ++i) {                                    \
                const size_t o = base + (size_t)(gr0 + i) * IMW + agc;        \
                p1[i] = img1[o];                                              \
                p2[i] = img2[o];                                              \
            }                                                                 \
        }                                                                     \
    }

// sx packing: sx01 = {sx[k=0], sx[k=1]}, sx23 = {sx[k=2], sx[k=3]}.
// Pair (0,1) valid for 1<=i<=10 with wp[i]; (2,3) for 3<=i<=12 with wp[i-2];
// single-k edges fall back to scalar fma. All i compile-time -> folds.
#define A_CONV(H_)                                                            \
    if (aon) {                                                                \
        f2 m12[4]  = {{0,0},{0,0},{0,0},{0,0}};                               \
        f2 qq[4]   = {{0,0},{0,0},{0,0},{0,0}};                               \
        f2 sx01 = {0, 0}, sx23 = {0, 0};                                      \
        _Pragma("unroll")                                                     \
        for (int i = 0; i < 14; ++i) {                                        \
            f2 x12; x12.x = p1[i]; x12.y = p2[i];                             \
            const f2 sq = x12 * x12;                                          \
            const float sxy = p1[i] * p2[i];                                  \
            f2 sxy2; sxy2.x = sxy; sxy2.y = sxy;                              \
            _Pragma("unroll")                                                 \
            for (int k = 0; k < 4; ++k) {                                     \
                const int j = i - k;                                          \
                if (j >= 0 && j < KW) {                                       \
                    const float w = wg[j];   /* SGPR operand */               \
                    const f2 w2 = {w, w};                                     \
                    m12[k] += w2 * x12;          /* v_pk_fma_f32 */           \
                    qq[k]  += w2 * sq;           /* v_pk_fma_f32 */           \
                }                                                             \
            }                                                                 \
            if (i >= 1 && i <= 10)       sx01 += wp[i] * sxy2;                \
            else if (i == 0)             sx01.x += wg[0]  * sxy;              \
            else if (i == 11)            sx01.y += wg[10] * sxy;              \
            if (i >= 3 && i <= 12)       sx23 += wp[i - 2] * sxy2;            \
            else if (i == 2)             sx23.x += wg[0]  * sxy;              \
            else if (i == 13)            sx23.y += wg[10] * sxy;              \
        }                                                                     \
        const float sxs[4] = {sx01.x, sx01.y, sx23.x, sx23.y};                \
        _Pragma("unroll")                                                     \
        for (int k = 0; k < 4; ++k) {                                         \
            f4 v;                                                             \
            v.x = m12[k].x; v.y = m12[k].y;                                   \
            v.z = qq[k].x;  v.w = qq[k].y;                                    \
            vv4[(ar0 + k) * S4 + ac] = v;        /* ds_write_b128 */          \
            vsx[(ar0 + k) * SX + ac] = sxs[k];   /* ds_write_b32  */          \
        }                                                                     \
    }

// Phase B: 2 output cols per thread, row = t&15 (varies within lane group!),
// cp = t>>4. asx packed: {k0,k1} via wp[cg] (valid 1<=cg<=10), edges scalar.
#define PHASE_B(H_)                                                           \
    {                                                                         \
        const int row = t & 15;                                               \
        const int cp  = t >> 4;              /* 0..31 */                      \
        const f4* __restrict__ p4 = &vv4[row * S4 + cp * 2];                  \
        const float* __restrict__ px = &vsx[row * SX + cp * 2];               \
        f2 am12[2] = {{0,0},{0,0}};                                           \
        f2 aqq[2]  = {{0,0},{0,0}};                                           \
        f2 asxp = {0, 0};                                                     \
        _Pragma("unroll")                                                     \
        for (int b = 0; b < 3; ++b) {                                         \
            f4 v[4]; float vx[4];                                             \
            _Pragma("unroll")                                                 \
            for (int cc = 0; cc < 4; ++cc) {                                  \
                v[cc]  = p4[b * 4 + cc];                                      \
                vx[cc] = px[b * 4 + cc];                                      \
            }                                                                 \
            _Pragma("unroll")                                                 \
            for (int cc = 0; cc < 4; ++cc) {                                  \
                const int cg = b * 4 + cc;                                    \
                f2 v12; v12.x = v[cc].x; v12.y = v[cc].y;                     \
                f2 vqq; vqq.x = v[cc].z; vqq.y = v[cc].w;                     \
                _Pragma("unroll")                                             \
                for (int k = 0; k < 2; ++k) {                                 \
                    const int j = cg - k;                                     \
                    if (j >= 0 && j < KW) {                                   \
                        const float w = wg[j];                                \
                        const f2 w2 = {w, w};                                 \
                        am12[k] += w2 * v12;                                  \
                        aqq[k]  += w2 * vqq;                                  \
                    }                                                         \
                }                                                             \
                f2 vx2; vx2.x = vx[cc]; vx2.y = vx[cc];                       \
                if (cg >= 1 && cg <= 10)  asxp += wp[cg] * vx2;               \
                else if (cg == 0)         asxp.x += wg[0]  * vx[cc];          \
                else if (cg == 11)        asxp.y += wg[10] * vx[cc];          \
            }                                                                 \
        }                                                                     \
        const float asx[2] = {asxp.x, asxp.y};                                \
        _Pragma("unroll")                                                     \
        for (int k = 0; k < 2; ++k) {                                         \
            const float mu1 = am12[k].x, mu2 = am12[k].y;                     \
            const float mu1sq = mu1 * mu1, mu2sq = mu2 * mu2;                 \
            const float mu12 = mu1 * mu2;                                     \
            const float sig1 = aqq[k].x - mu1sq;                              \
            const float sig2 = aqq[k].y - mu2sq;                              \
            const float sig12 = asx[k] - mu12;                                \
            const float num = (2.f * mu12 + C1v) * (2.f * sig12 + C2v);       \
            const float den = (mu1sq + mu2sq + C1v) * (sig1 + sig2 + C2v);    \
            float r = __builtin_amdgcn_rcpf(den);                             \
            r = r * (2.f - den * r);             /* Newton -> ~fp32 exact */  \
            lsum += num * r;                                                  \
        }                                                                     \
    }

__global__ __launch_bounds__(512, 4) void ssim_main(
    const float* __restrict__ img1, const float* __restrict__ img2,
    const float* __restrict__ window, float* __restrict__ partial)
{
    __shared__ f4 vv4[HROWS * S4];       // 19712 B
    __shared__ float vsx[HROWS * SX];    //  4928 B -> 24.7 KB total
    __shared__ float g[KW];
    __shared__ float wsum[8];

    const int t = threadIdx.x;

    const int plane = blockIdx.z;
    const size_t base = (size_t)plane * IMH * IMW;
    const int ix0 = blockIdx.x * TW - PAD;
    const int iy0 = blockIdx.y * TH - PAD;

    const bool aon = t < ICOLS * 4;               // 296 phase-A threads
    const int ac  = t % ICOLS;                    // col (valid when aon)
    const int ar0 = (t / ICOLS) * 4;              // local row base in half
    const int agc = ix0 + ac;

    const bool interior = (ix0 >= 0) && (ix0 + ICOLS <= IMW) &&
                          (iy0 >= 0) && (iy0 + TH + KW - 1 <= IMH);

    float p1[14], p2[14];                         // A-phase load regs

    // Issue half-0 loads first: latency hides under window prep + barrier.
    if (interior) { A_LOAD(false, 0) } else { A_LOAD(true, 0) }

    // Separable 1D Gaussian = row-sums of the 2D window (columns sum to 1).
    if (t < KW) {
        float s = 0.f;
        for (int j = 0; j < KW; ++j) s += window[(t * KW + j) * 3];
        g[t] = s;
    }
    __syncthreads();

    // Weights wave-uniform -> SGPRs (VALU reads one SGPR operand free).
    float wg[KW];
#pragma unroll
    for (int j = 0; j < KW; ++j) {
        const int bi = __builtin_amdgcn_readfirstlane(__float_as_int(g[j]));
        wg[j] = __int_as_float(bi);
    }
    // Packed weight pairs wp[j] = {w[j], w[j-1]} for pk-fma sx accumulation.
    f2 wp[KW];
#pragma unroll
    for (int j = 1; j < KW; ++j) { wp[j].x = wg[j]; wp[j].y = wg[j - 1]; }

    const float C1v = 0.0001f;
    const float C2v = 0.0009f;
    float lsum = 0.f;

    // ---- Half 0 compute ----
    A_CONV(0)
    __syncthreads();

    // ---- Issue half-1 loads, then run B0 ----
    if (interior) { A_LOAD(false, 1) } else { A_LOAD(true, 1) }
    PHASE_B(0)
    __syncthreads();

    // ---- Half 1 compute ----
    A_CONV(1)
    __syncthreads();
    PHASE_B(1)

    // ---- Reduction: wave shuffle -> cross-wave LDS -> per-block store.
#pragma unroll
    for (int off = 32; off > 0; off >>= 1) lsum += __shfl_down(lsum, off, 64);
    if ((t & 63) == 0) wsum[t >> 6] = lsum;
    __syncthreads();
    if (t == 0) {
        float bs = 0.f;
#pragma unroll
        for (int w = 0; w < 8; ++w) bs += wsum[w];
        unsigned bid = (blockIdx.z * gridDim.y + blockIdx.y) * gridDim.x
                     + blockIdx.x;
        partial[bid] = bs;
    }
}

__global__ __launch_bounds__(1024) void ssim_reduce(
    const float* __restrict__ partial, float* __restrict__ out, double inv_n)
{
    __shared__ double dsum[16];
    const int t = threadIdx.x;
    double s = 0.0;
    for (int i = t; i < NBLK; i += 1024) s += (double)partial[i];
#pragma unroll
    for (int off = 32; off > 0; off >>= 1) s += __shfl_down(s, off, 64);
    if ((t & 63) == 0) dsum[t >> 6] = s;
    __syncthreads();
    if (t == 0) {
        double tot = 0.0;
#pragma unroll
        for (int w = 0; w < 16; ++w) tot += dsum[w];
        out[0] = (float)(tot * inv_n);
    }
}

extern "C" void kernel_launch(void* const* d_in, const int* in_sizes, int n_in,
                              void* d_out, int out_size, void* d_ws, size_t ws_size,
                              hipStream_t stream) {
    const float* img1   = (const float*)d_in[0];
    const float* img2   = (const float*)d_in[1];
    const float* window = (const float*)d_in[2];
    float* out = (float*)d_out;
    float* partial = (float*)d_ws;               // 6144 floats = 24 KB

    const int nplanes = in_sizes[0] / (IMH * IMW);   // 48
    const long long total = (long long)in_sizes[0];

    dim3 grid(IMW / TW, IMH / TH, nplanes);      // 8 x 16 x 48 = 6144
    ssim_main<<<grid, 512, 0, stream>>>(img1, img2, window, partial);
    ssim_reduce<<<1, 1024, 0, stream>>>(partial, out, 1.0 / (double)total);
}

// Round 13
// 158.988 us; speedup vs baseline: 2.9763x; 1.0143x over previous
//
#include <hip/hip_runtime.h>

#define KW 11
#define PAD 5
#define TW 64              // tile width (halo overhead 74/64 = 1.16x)
#define TH 32
#define HROWS 16           // rows per half-tile
#define ICOLS 74           // input col span incl. halo (TW + KW - 1)
#define S4 77              // f4-plane row stride (308 words = 20 mod 32 -> 8-lane b128 starts all distinct)
#define SX 77              // sx-plane row stride
#define IMH 512
#define IMW 512
#define NBLK 6144          // 8 x 16 x 48
#define NCONV 296          // ICOLS*4 phase-A conv tasks
#define LBASE 320          // loader threads start (wave-aligned: waves 5..7)
#define NLOAD 192          // loader thread count
#define RAWROWS 26         // A1 input rows union (16 out + 10 halo)
#define RAWV (2*RAWROWS*74)   // 3848 raw values (img-interleaved)
#define LTASK 21           // ceil(3848/192)

typedef float f2 __attribute__((ext_vector_type(2)));
typedef float f4 __attribute__((ext_vector_type(4)));

// LDS: vv4[row*S4+col] = (mu1,mu2,q11,q22) f4; vsx = x1*x2; raw = half-1
// input, img-interleaved: raw[2*(row*74+col)+img].
// Schedule: convs(t<296): A0.load(reg) -> A0.conv | loaders(t>=320): raw
// load -> LDS | bar | B0(all) | bar | A1.conv reads raw from LDS | bar | B1.
//
// R6: reg-hoisted loads (MLP) = the lever. R8: never DEMAND occupancy
// (min-waves spill disaster); cap-only bounds; WRITE_SIZE > ~1 MB = spill.
// R10: compiler sinks same-thread prefetch -> T14 impossible intra-thread.
// R12: bank-conflict counter invariant under remap -> benign/elsewhere; we
// are stall-bound, not VALU-bound.
// R13: cross-thread T14 — idle waves 5-7 stage A1's input union (3848 loads
// vs 8288 redundant), A1 conv reads LDS -> no exposed HBM wait after half 0.

#define A_LOAD(EDGE_)                                                         \
    if (t < NCONV) {                                                          \
        const int gr0 = iy0 + ar0;                                            \
        if (EDGE_) {                                                          \
            const bool cok = (agc >= 0) && (agc < IMW);                       \
            _Pragma("unroll")                                                 \
            for (int i = 0; i < 14; ++i) {                                    \
                const int gr = gr0 + i;                                       \
                const bool ok = cok && (gr >= 0) && (gr < IMH);               \
                const size_t o = base + (size_t)(ok ? gr : 0) * IMW           \
                               + (ok ? agc : 0);                              \
                p1[i] = ok ? img1[o] : 0.f;                                   \
                p2[i] = ok ? img2[o] : 0.f;                                   \
            }                                                                 \
        } else {                                                              \
            _Pragma("unroll")                                                 \
            for (int i = 0; i < 14; ++i) {                                    \
                const size_t o = base + (size_t)(gr0 + i) * IMW + agc;        \
                p1[i] = img1[o];                                              \
                p2[i] = img2[o];                                              \
            }                                                                 \
        }                                                                     \
    }

// Loaders: 21 tasks each, o = lidx + 192*s; img = o&1 (per-thread constant
// since 192 even), row = o/148, col = (o%148)>>1. Only s==20 can exceed RAWV.
#define RAW_STAGE(EDGE_)                                                      \
    {                                                                         \
        float rv[LTASK];                                                      \
        _Pragma("unroll")                                                     \
        for (int s = 0; s < LTASK; ++s) {                                     \
            const int o = lidx + NLOAD * s;                                   \
            const int row = o / 148;                                          \
            const int col = (o % 148) >> 1;                                   \
            const int gr = iy1 + row;       /* iy1 >= 11: no top check */     \
            const int gc = ix0 + col;                                         \
            const float* sp = (o & 1) ? img2 : img1;                          \
            bool ok = (s != LTASK - 1) || (o < RAWV);                         \
            if (EDGE_) ok = ok && (gr < IMH) && (gc >= 0) && (gc < IMW);      \
            const size_t go = base + (size_t)(ok ? gr : 0) * IMW              \
                            + (ok ? gc : 0);                                  \
            rv[s] = ok ? sp[go] : 0.f;                                        \
        }                                                                     \
        _Pragma("unroll")                                                     \
        for (int s = 0; s < LTASK; ++s) {                                     \
            const int o = lidx + NLOAD * s;                                   \
            if (s != LTASK - 1 || o < RAWV) raw[o] = rv[s];                   \
        }                                                                     \
    }

// Shared conv body: consumes x12 (f2 per row i), writes vv4/vsx.
#define A_CONV_BODY(GETX_)                                                    \
    {                                                                         \
        f2 m12[4]  = {{0,0},{0,0},{0,0},{0,0}};                               \
        f2 qq[4]   = {{0,0},{0,0},{0,0},{0,0}};                               \
        f2 sx01 = {0, 0}, sx23 = {0, 0};                                      \
        _Pragma("unroll")                                                     \
        for (int i = 0; i < 14; ++i) {                                        \
            f2 x12; GETX_;                                                    \
            const f2 sq = x12 * x12;                                          \
            const float sxy = x12.x * x12.y;                                  \
            f2 sxy2; sxy2.x = sxy; sxy2.y = sxy;                              \
            _Pragma("unroll")                                                 \
            for (int k = 0; k < 4; ++k) {                                     \
                const int j = i - k;                                          \
                if (j >= 0 && j < KW) {                                       \
                    const float w = wg[j];   /* SGPR operand */               \
                    const f2 w2 = {w, w};                                     \
                    m12[k] += w2 * x12;          /* v_pk_fma_f32 */           \
                    qq[k]  += w2 * sq;           /* v_pk_fma_f32 */           \
                }                                                             \
            }                                                                 \
            if (i >= 1 && i <= 10)       sx01 += wp[i] * sxy2;                \
            else if (i == 0)             sx01.x += wg[0]  * sxy;              \
            else if (i == 11)            sx01.y += wg[10] * sxy;              \
            if (i >= 3 && i <= 12)       sx23 += wp[i - 2] * sxy2;            \
            else if (i == 2)             sx23.x += wg[0]  * sxy;              \
            else if (i == 13)            sx23.y += wg[10] * sxy;              \
        }                                                                     \
        const float sxs[4] = {sx01.x, sx01.y, sx23.x, sx23.y};                \
        _Pragma("unroll")                                                     \
        for (int k = 0; k < 4; ++k) {                                         \
            f4 v;                                                             \
            v.x = m12[k].x; v.y = m12[k].y;                                   \
            v.z = qq[k].x;  v.w = qq[k].y;                                    \
            vv4[(ar0 + k) * S4 + ac] = v;        /* ds_write_b128 */          \
            vsx[(ar0 + k) * SX + ac] = sxs[k];   /* ds_write_b32  */          \
        }                                                                     \
    }

// Phase B (unchanged from R12): row = t&15, cp = t>>4; packed-weight sx.
#define PHASE_B(H_)                                                           \
    {                                                                         \
        const int row = t & 15;                                               \
        const int cp  = t >> 4;              /* 0..31 */                      \
        const f4* __restrict__ p4 = &vv4[row * S4 + cp * 2];                  \
        const float* __restrict__ px = &vsx[row * SX + cp * 2];               \
        f2 am12[2] = {{0,0},{0,0}};                                           \
        f2 aqq[2]  = {{0,0},{0,0}};                                           \
        f2 asxp = {0, 0};                                                     \
        _Pragma("unroll")                                                     \
        for (int b = 0; b < 3; ++b) {                                         \
            f4 v[4]; float vx[4];                                             \
            _Pragma("unroll")                                                 \
            for (int cc = 0; cc < 4; ++cc) {                                  \
                v[cc]  = p4[b * 4 + cc];                                      \
                vx[cc] = px[b * 4 + cc];                                      \
            }                                                                 \
            _Pragma("unroll")                                                 \
            for (int cc = 0; cc < 4; ++cc) {                                  \
                const int cg = b * 4 + cc;                                    \
                f2 v12; v12.x = v[cc].x; v12.y = v[cc].y;                     \
                f2 vqq; vqq.x = v[cc].z; vqq.y = v[cc].w;                     \
                _Pragma("unroll")                                             \
                for (int k = 0; k < 2; ++k) {                                 \
                    const int j = cg - k;                                     \
                    if (j >= 0 && j < KW) {                                   \
                        const float w = wg[j];                                \
                        const f2 w2 = {w, w};                                 \
                        am12[k] += w2 * v12;                                  \
                        aqq[k]  += w2 * vqq;                                  \
                    }                                                         \
                }                                                             \
                f2 vx2; vx2.x = vx[cc]; vx2.y = vx[cc];                       \
                if (cg >= 1 && cg <= 10)  asxp += wp[cg] * vx2;               \
                else if (cg == 0)         asxp.x += wg[0]  * vx[cc];          \
                else if (cg == 11)        asxp.y += wg[10] * vx[cc];          \
            }                                                                 \
        }                                                                     \
        const float asx[2] = {asxp.x, asxp.y};                                \
        _Pragma("unroll")                                                     \
        for (int k = 0; k < 2; ++k) {                                         \
            const float mu1 = am12[k].x, mu2 = am12[k].y;                     \
            const float mu1sq = mu1 * mu1, mu2sq = mu2 * mu2;                 \
            const float mu12 = mu1 * mu2;                                     \
            const float sig1 = aqq[k].x - mu1sq;                              \
            const float sig2 = aqq[k].y - mu2sq;                              \
            const float sig12 = asx[k] - mu12;                                \
            const float num = (2.f * mu12 + C1v) * (2.f * sig12 + C2v);       \
            const float den = (mu1sq + mu2sq + C1v) * (sig1 + sig2 + C2v);    \
            float r = __builtin_amdgcn_rcpf(den);                             \
            r = r * (2.f - den * r);             /* Newton -> ~fp32 exact */  \
            lsum += num * r;                                                  \
        }                                                                     \
    }

__global__ __launch_bounds__(512, 4) void ssim_main(
    const float* __restrict__ img1, const float* __restrict__ img2,
    const float* __restrict__ window, float* __restrict__ partial)
{
    __shared__ f4 vv4[HROWS * S4];                 // 19712 B
    __shared__ float vsx[HROWS * SX];              //  4928 B
    __shared__ __align__(16) float raw[RAWV];      // 15392 B -> ~40.1 KB, 4 blk/CU
    __shared__ float g[KW];
    __shared__ float wsum[8];

    const int t = threadIdx.x;

    const int plane = blockIdx.z;
    const size_t base = (size_t)plane * IMH * IMW;
    const int ix0 = blockIdx.x * TW - PAD;
    const int iy0 = blockIdx.y * TH - PAD;
    const int iy1 = iy0 + HROWS;                  // first A1 input row (>= 11)

    const int ac  = t % ICOLS;                    // conv col (valid t < NCONV)
    const int ar0 = (t / ICOLS) * 4;              // conv local row base
    const int agc = ix0 + ac;
    const int lidx = t - LBASE;                   // loader index (valid t >= LBASE)

    const bool interior = (ix0 >= 0) && (ix0 + ICOLS <= IMW) &&
                          (iy0 >= 0) && (iy0 + TH + KW - 1 <= IMH);

    float p1[14], p2[14];                         // A0 reg-hoisted inputs

    // Conv threads issue half-0 loads; loader waves (5..7) stage half-1 raw.
    if (t < LBASE) {
        if (interior) { A_LOAD(false) } else { A_LOAD(true) }
    } else {
        if (interior) { RAW_STAGE(false) } else { RAW_STAGE(true) }
    }

    // Separable 1D Gaussian = row-sums of the 2D window (columns sum to 1).
    if (t < KW) {
        float s = 0.f;
        for (int j = 0; j < KW; ++j) s += window[(t * KW + j) * 3];
        g[t] = s;
    }
    __syncthreads();

    // Weights wave-uniform -> SGPRs (VALU reads one SGPR operand free).
    float wg[KW];
#pragma unroll
    for (int j = 0; j < KW; ++j) {
        const int bi = __builtin_amdgcn_readfirstlane(__float_as_int(g[j]));
        wg[j] = __int_as_float(bi);
    }
    // Packed weight pairs wp[j] = {w[j], w[j-1]} for pk-fma sx accumulation.
    f2 wp[KW];
#pragma unroll
    for (int j = 1; j < KW; ++j) { wp[j].x = wg[j]; wp[j].y = wg[j - 1]; }

    const float C1v = 0.0001f;
    const float C2v = 0.0009f;
    float lsum = 0.f;

    // ---- Half 0 conv (from regs) ----
    if (t < NCONV) A_CONV_BODY(x12.x = p1[i]; x12.y = p2[i];)
    __syncthreads();

    PHASE_B(0)
    __syncthreads();

    // ---- Half 1 conv (from raw LDS: f2 img-interleaved reads) ----
    if (t < NCONV)
        A_CONV_BODY(x12 = *reinterpret_cast<const f2*>(
                        &raw[((ar0 + i) * 74 + ac) * 2]);)
    __syncthreads();

    PHASE_B(1)

    // ---- Reduction: wave shuffle -> cross-wave LDS -> per-block store.
#pragma unroll
    for (int off = 32; off > 0; off >>= 1) lsum += __shfl_down(lsum, off, 64);
    if ((t & 63) == 0) wsum[t >> 6] = lsum;
    __syncthreads();
    if (t == 0) {
        float bs = 0.f;
#pragma unroll
        for (int w = 0; w < 8; ++w) bs += wsum[w];
        unsigned bid = (blockIdx.z * gridDim.y + blockIdx.y) * gridDim.x
                     + blockIdx.x;
        partial[bid] = bs;
    }
}

__global__ __launch_bounds__(1024) void ssim_reduce(
    const float* __restrict__ partial, float* __restrict__ out, double inv_n)
{
    __shared__ double dsum[16];
    const int t = threadIdx.x;
    double s = 0.0;
    for (int i = t; i < NBLK; i += 1024) s += (double)partial[i];
#pragma unroll
    for (int off = 32; off > 0; off >>= 1) s += __shfl_down(s, off, 64);
    if ((t & 63) == 0) dsum[t >> 6] = s;
    __syncthreads();
    if (t == 0) {
        double tot = 0.0;
#pragma unroll
        for (int w = 0; w < 16; ++w) tot += dsum[w];
        out[0] = (float)(tot * inv_n);
    }
}

extern "C" void kernel_launch(void* const* d_in, const int* in_sizes, int n_in,
                              void* d_out, int out_size, void* d_ws, size_t ws_size,
                              hipStream_t stream) {
    const float* img1   = (const float*)d_in[0];
    const float* img2   = (const float*)d_in[1];
    const float* window = (const float*)d_in[2];
    float* out = (float*)d_out;
    float* partial = (float*)d_ws;               // 6144 floats = 24 KB

    const int nplanes = in_sizes[0] / (IMH * IMW);   // 48
    const long long total = (long long)in_sizes[0];

    dim3 grid(IMW / TW, IMH / TH, nplanes);      // 8 x 16 x 48 = 6144
    ssim_main<<<grid, 512, 0, stream>>>(img1, img2, window, partial);
    ssim_reduce<<<1, 1024, 0, stream>>>(partial, out, 1.0 / (double)total);
}